// Round 4
// baseline (140.305 us; speedup 1.0000x reference)
//
#include <hip/hip_runtime.h>
#include <stdint.h>

#define INDIM   1024
#define OUTDIM  1024
#define BTILE   16          // batch rows per block
#define SLAB_U32 12         // uint32s per slab row = 48B (8 used + 4 pad)

// ---------------- sort-by-output-column (CSC build) ----------------

__global__ void k_hist(const int* __restrict__ ind_out, int* __restrict__ hist, int nnz) {
    int k = blockIdx.x * 256 + threadIdx.x;
    if (k < nnz) atomicAdd(&hist[ind_out[k]], 1);
}

__global__ void k_scan(const int* __restrict__ hist, int* __restrict__ col_ptr,
                       int* __restrict__ cursor) {
    __shared__ int s[OUTDIM];
    int t = threadIdx.x;
    int cnt = hist[t];
    s[t] = cnt;
    for (int off = 1; off < OUTDIM; off <<= 1) {
        __syncthreads();
        int v = (t >= off) ? s[t - off] : 0;
        __syncthreads();
        s[t] += v;
    }
    __syncthreads();
    col_ptr[t + 1] = s[t];          // inclusive -> col_ptr[o+1]
    if (t == 0) col_ptr[0] = 0;
    cursor[t] = s[t] - cnt;         // exclusive prefix = scatter cursor
}

__global__ void k_scatter(const int* __restrict__ ind_in, const int* __restrict__ ind_out,
                          const float* __restrict__ w, int* __restrict__ cursor,
                          int2* __restrict__ sorted, int nnz) {
    int k = blockIdx.x * 256 + threadIdx.x;
    if (k < nnz) {
        int o = ind_out[k];
        int pos = atomicAdd(&cursor[o], 1);
        int2 e;
        e.x = ind_in[k] * (SLAB_U32 * 4);   // pre-scaled LDS byte offset of row i
        e.y = __float_as_int(w[k]);
        sorted[pos] = e;
    }
}

// ---------------- main SpMM ----------------
// block: 16 batch rows x all 1024 outputs. slab word r of row i packs batch
// rows (2r, 2r+1) of input column i as bf16x2 (low = even row, high = odd).
// thread t: boct = t&1 (which 8-row half), og = t>>1; outputs o = og + 512*j.

// Macro param W, not w: uint4 has a member .w (R0 compile bug).
#define FMA8E(f, W)                                                             \
    acc[0] = fmaf(__uint_as_float((f).x << 16),          (W), acc[0]);          \
    acc[1] = fmaf(__uint_as_float((f).x & 0xFFFF0000u),  (W), acc[1]);          \
    acc[2] = fmaf(__uint_as_float((f).y << 16),          (W), acc[2]);          \
    acc[3] = fmaf(__uint_as_float((f).y & 0xFFFF0000u),  (W), acc[3]);          \
    acc[4] = fmaf(__uint_as_float((f).z << 16),          (W), acc[4]);          \
    acc[5] = fmaf(__uint_as_float((f).z & 0xFFFF0000u),  (W), acc[5]);          \
    acc[6] = fmaf(__uint_as_float((f).w << 16),          (W), acc[6]);          \
    acc[7] = fmaf(__uint_as_float((f).w & 0xFFFF0000u),  (W), acc[7]);

__device__ __forceinline__ uint32_t bf16pack(float x, float y) {
    uint32_t ux = __float_as_uint(x);
    ux = ((ux + 0x7FFFu + ((ux >> 16) & 1u)) >> 16) & 0xFFFFu;   // RNE, low half
    uint32_t uy = __float_as_uint(y);
    uy = (uy + 0x7FFFu + ((uy >> 16) & 1u)) & 0xFFFF0000u;       // RNE, high half
    return ux | uy;
}

__global__ __launch_bounds__(1024, 4) void k_spmm(
    const float* __restrict__ in, const int2* __restrict__ sorted,
    const int* __restrict__ col_ptr, const float* __restrict__ bias,
    float* __restrict__ out)
{
    __shared__ uint32_t slab[INDIM * SLAB_U32];   // 48 KB

    const int t  = threadIdx.x;
    const int b0 = blockIdx.x * BTILE;

    // ---- stage: thread t owns input column t (direct, no transpose buf) ----
    // For each r, the 1024 threads read one full input row -> coalesced.
    {
        const float* colp = in + (size_t)b0 * INDIM + t;
        #pragma unroll
        for (int r = 0; r < 8; r++) {
            float v0 = colp[(size_t)(2 * r)     * INDIM];
            float v1 = colp[(size_t)(2 * r + 1) * INDIM];
            slab[t * SLAB_U32 + r] = bf16pack(v0, v1);
        }
    }
    __syncthreads();

    // ---- gather/accumulate per output column ----
    const int boct = t & 1;            // which 8-row half of the tile
    const int og   = t >> 1;           // [0,512)
    const int boff = boct * 16;        // byte offset within slab row (words 0-3 / 4-7)
    const char* slab_b = (const char*)slab;

    for (int j = 0; j < 2; j++) {
        const int o  = og + 512 * j;
        int k        = col_ptr[o];
        const int ke = col_ptr[o + 1];
        float acc[8] = {0.f, 0.f, 0.f, 0.f, 0.f, 0.f, 0.f, 0.f};

        for (; k + 2 <= ke; k += 2) {
            int2 e0 = sorted[k];
            int2 e1 = sorted[k + 1];
            uint4 f0 = *(const uint4*)(slab_b + e0.x + boff);
            uint4 f1 = *(const uint4*)(slab_b + e1.x + boff);
            float w0 = __int_as_float(e0.y);
            float w1 = __int_as_float(e1.y);
            FMA8E(f0, w0);
            FMA8E(f1, w1);
        }
        if (k < ke) {
            int2 e0 = sorted[k];
            uint4 f0 = *(const uint4*)(slab_b + e0.x + boff);
            float w0 = __int_as_float(e0.y);
            FMA8E(f0, w0);
        }

        const float bv = bias[o];
        float* op = out + (size_t)(b0 + boct * 8) * OUTDIM + o;
        #pragma unroll
        for (int e = 0; e < 8; e++) op[(size_t)e * OUTDIM] = acc[e] + bv;
    }
}

// ---------------- launcher ----------------

extern "C" void kernel_launch(void* const* d_in, const int* in_sizes, int n_in,
                              void* d_out, int out_size, void* d_ws, size_t ws_size,
                              hipStream_t stream) {
    const float* input  = (const float*)d_in[0];
    const float* weight = (const float*)d_in[1];
    const float* bias   = (const float*)d_in[2];
    const int*   ind_in  = (const int*)d_in[3];
    const int*   ind_out = (const int*)d_in[4];
    float* out = (float*)d_out;

    const int nnz   = in_sizes[1];
    const int batch = out_size / OUTDIM;

    // R3 fix: col_ptr is 1025 ints = 4100 B. The old layout gave it 4096 B,
    // so col_ptr[1024] aliased cursor[0] -> k_scatter's atomics clobbered the
    // end pointer of column 1023 -> that column summed 0 entries -> the
    // bit-identical absmax 1.187 (= max |missing column sum|) across R1/R2.
    char* ws = (char*)d_ws;
    int*  hist    = (int*)ws;                 // [1024]   @ 0
    int*  col_ptr = (int*)(ws + 4096);        // [1025]   @ 4096  (8 KB slot)
    int*  cursor  = (int*)(ws + 12288);       // [1024]   @ 12288
    int2* sorted  = (int2*)(ws + 16384);      // [nnz]    @ 16384

    (void)hipMemsetAsync(hist, 0, OUTDIM * sizeof(int), stream);
    k_hist<<<(nnz + 255) / 256, 256, 0, stream>>>(ind_out, hist, nnz);
    k_scan<<<1, OUTDIM, 0, stream>>>(hist, col_ptr, cursor);
    k_scatter<<<(nnz + 255) / 256, 256, 0, stream>>>(ind_in, ind_out, weight, cursor, sorted, nnz);
    k_spmm<<<batch / BTILE, 1024, 0, stream>>>(input, sorted, col_ptr, bias, out);
}

// Round 5
// 112.128 us; speedup vs baseline: 1.2513x; 1.2513x over previous
//
#include <hip/hip_runtime.h>
#include <stdint.h>

#define INDIM   1024
#define OUTDIM  1024
#define BTILE   16          // batch rows per block
#define SLAB_U32 12         // uint32s per slab row = 48B (8 used + 4 pad, 16B-aligned)
#define ELL_MAX 128         // capacity per column (max count ~75 expected)

// ---------------- ELL-transposed build ----------------
// No hist/scan needed: atomic cursors from zero give within-column positions;
// the final cursor value IS the per-column count consumed by k_spmm.
// Entry k of column o lives at ell[k*1024 + o] -> spmm's step-k load over a
// wave's 32 consecutive columns is one coalesced 256B transaction (R4 fix:
// the CSC layout made every wave-load touch ~32 distinct cache lines).

__global__ void k_scatter(const int* __restrict__ ind_in, const int* __restrict__ ind_out,
                          const float* __restrict__ w, int* __restrict__ cursor,
                          int2* __restrict__ ell, int nnz) {
    int k = blockIdx.x * 256 + threadIdx.x;
    if (k < nnz) {
        int o = ind_out[k];
        int pos = atomicAdd(&cursor[o], 1);
        if (pos < ELL_MAX) {
            int2 e;
            e.x = ind_in[k] * (SLAB_U32 * 4);   // pre-scaled LDS byte offset of row i
            e.y = __float_as_int(w[k]);
            ell[(size_t)pos * OUTDIM + o] = e;
        }
    }
}

// ---------------- main SpMM ----------------
// block: 16 batch rows x all 1024 outputs. slab word r of row i packs batch
// rows (2r, 2r+1) of input column i as bf16x2 (low = even row, high = odd).
// thread t: boct = t&1 (which 8-row half), og = t>>1; outputs o = og + 512*j.

// Macro param W, not w: uint4 has a member .w (R0 compile bug).
#define FMA8E(f, W)                                                             \
    acc[0] = fmaf(__uint_as_float((f).x << 16),          (W), acc[0]);          \
    acc[1] = fmaf(__uint_as_float((f).x & 0xFFFF0000u),  (W), acc[1]);          \
    acc[2] = fmaf(__uint_as_float((f).y << 16),          (W), acc[2]);          \
    acc[3] = fmaf(__uint_as_float((f).y & 0xFFFF0000u),  (W), acc[3]);          \
    acc[4] = fmaf(__uint_as_float((f).z << 16),          (W), acc[4]);          \
    acc[5] = fmaf(__uint_as_float((f).z & 0xFFFF0000u),  (W), acc[5]);          \
    acc[6] = fmaf(__uint_as_float((f).w << 16),          (W), acc[6]);          \
    acc[7] = fmaf(__uint_as_float((f).w & 0xFFFF0000u),  (W), acc[7]);

__device__ __forceinline__ uint32_t bf16pack(float x, float y) {
    uint32_t ux = __float_as_uint(x);
    ux = ((ux + 0x7FFFu + ((ux >> 16) & 1u)) >> 16) & 0xFFFFu;   // RNE, low half
    uint32_t uy = __float_as_uint(y);
    uy = (uy + 0x7FFFu + ((uy >> 16) & 1u)) & 0xFFFF0000u;       // RNE, high half
    return ux | uy;
}

__global__ __launch_bounds__(1024, 4) void k_spmm(
    const float* __restrict__ in, const int2* __restrict__ ell,
    const int* __restrict__ cnt, const float* __restrict__ bias,
    float* __restrict__ out)
{
    __shared__ uint32_t slab[INDIM * SLAB_U32];   // 48 KB

    const int t  = threadIdx.x;
    const int b0 = blockIdx.x * BTILE;

    // ---- stage: thread t owns input column t; per r the block reads one
    // full input row -> coalesced.
    {
        const float* colp = in + (size_t)b0 * INDIM + t;
        #pragma unroll
        for (int r = 0; r < 8; r++) {
            float v0 = colp[(size_t)(2 * r)     * INDIM];
            float v1 = colp[(size_t)(2 * r + 1) * INDIM];
            slab[t * SLAB_U32 + r] = bf16pack(v0, v1);
        }
    }
    __syncthreads();

    // ---- gather/accumulate per output column ----
    const int boct = t & 1;            // which 8-row half of the tile
    const int og   = t >> 1;           // [0,512)
    const int boff = boct * 16;        // byte offset within slab row (words 0-3 / 4-7)
    const char* slab_b = (const char*)slab;

    for (int j = 0; j < 2; j++) {
        const int o  = og + 512 * j;
        const int n  = cnt[o];
        const int2* ep = ell + o;      // stride OUTDIM entries between steps
        float acc[8] = {0.f, 0.f, 0.f, 0.f, 0.f, 0.f, 0.f, 0.f};

        int k = 0;
        for (; k + 2 <= n; k += 2) {
            int2 e0 = ep[(size_t)k * OUTDIM];
            int2 e1 = ep[(size_t)(k + 1) * OUTDIM];
            uint4 f0 = *(const uint4*)(slab_b + e0.x + boff);
            uint4 f1 = *(const uint4*)(slab_b + e1.x + boff);
            float w0 = __int_as_float(e0.y);
            float w1 = __int_as_float(e1.y);
            FMA8E(f0, w0);
            FMA8E(f1, w1);
        }
        if (k < n) {
            int2 e0 = ep[(size_t)k * OUTDIM];
            uint4 f0 = *(const uint4*)(slab_b + e0.x + boff);
            float w0 = __int_as_float(e0.y);
            FMA8E(f0, w0);
        }

        const float bv = bias[o];
        float* op = out + (size_t)(b0 + boct * 8) * OUTDIM + o;
        #pragma unroll
        for (int e = 0; e < 8; e++) op[(size_t)e * OUTDIM] = acc[e] + bv;
    }
}

// ---------------- launcher ----------------

extern "C" void kernel_launch(void* const* d_in, const int* in_sizes, int n_in,
                              void* d_out, int out_size, void* d_ws, size_t ws_size,
                              hipStream_t stream) {
    const float* input  = (const float*)d_in[0];
    const float* weight = (const float*)d_in[1];
    const float* bias   = (const float*)d_in[2];
    const int*   ind_in  = (const int*)d_in[3];
    const int*   ind_out = (const int*)d_in[4];
    float* out = (float*)d_out;

    const int nnz   = in_sizes[1];
    const int batch = out_size / OUTDIM;

    char* ws = (char*)d_ws;
    int*  cursor = (int*)ws;                  // [1024]          @ 0
    int2* ell    = (int2*)(ws + 4096);        // [ELL_MAX*1024]  @ 4096 (1 MB)

    (void)hipMemsetAsync(cursor, 0, OUTDIM * sizeof(int), stream);
    k_scatter<<<(nnz + 255) / 256, 256, 0, stream>>>(ind_in, ind_out, weight, cursor, ell, nnz);
    k_spmm<<<batch / BTILE, 1024, 0, stream>>>(input, ell, cursor, bias, out);
}